// Round 5
// baseline (205.509 us; speedup 1.0000x reference)
//
#include <hip/hip_runtime.h>
#include <hip/hip_bf16.h>
#include <math.h>

typedef __bf16 bf16_t;
typedef __attribute__((ext_vector_type(8))) __bf16 bf16x8;
typedef __attribute__((ext_vector_type(4))) __bf16 bf16x4;
typedef __attribute__((ext_vector_type(4))) float f32x4;
typedef __attribute__((ext_vector_type(4))) int i32x4;

#define B_DIM 2
#define S_DIM 2048
#define H_DIM 16
#define DK 64
#define DM 1024
#define KDIM 1024

#define MFMA(a, b, c) __builtin_amdgcn_mfma_f32_16x16x32_bf16((a), (b), (c), 0, 0, 0)

__device__ __forceinline__ void gload_lds16(const bf16_t* g, bf16_t* l) {
    __builtin_amdgcn_global_load_lds(
        (const __attribute__((address_space(1))) void*)g,
        (__attribute__((address_space(3))) void*)l, 16, 0, 0);
}

// exact-count 16B global load to VGPRs (inline asm so vmcnt bookkeeping is deterministic)
__device__ __forceinline__ i32x4 gload_b128(const bf16_t* p) {
    i32x4 r;
    asm volatile("global_load_dwordx4 %0, %1, off" : "=v"(r) : "v"(p) : "memory");
    return r;
}

// ---------------- fp32 -> bf16 convert ----------------
__global__ void cvt_kernel(const float* __restrict__ src, bf16_t* __restrict__ dst, int n) {
    int i = (blockIdx.x * blockDim.x + threadIdx.x) * 4;
    if (i >= n) return;
    float4 v = *reinterpret_cast<const float4*>(src + i);
    bf16x4 o;
    o[0] = (__bf16)v.x; o[1] = (__bf16)v.y; o[2] = (__bf16)v.z; o[3] = (__bf16)v.w;
    *reinterpret_cast<bf16x4*>(dst + i) = o;
}

__global__ void cvt4_kernel(const float* __restrict__ s0, const float* __restrict__ s1,
                            const float* __restrict__ s2, const float* __restrict__ s3,
                            bf16_t* __restrict__ d0, bf16_t* __restrict__ d1,
                            bf16_t* __restrict__ d2, bf16_t* __restrict__ d3, int n) {
    const float* s; bf16_t* d;
    switch (blockIdx.y) {
        case 0: s = s0; d = d0; break;
        case 1: s = s1; d = d1; break;
        case 2: s = s2; d = d2; break;
        default: s = s3; d = d3; break;
    }
    int i = (blockIdx.x * blockDim.x + threadIdx.x) * 4;
    if (i >= n) return;
    float4 v = *reinterpret_cast<const float4*>(s + i);
    bf16x4 o;
    o[0] = (__bf16)v.x; o[1] = (__bf16)v.y; o[2] = (__bf16)v.z; o[3] = (__bf16)v.w;
    *reinterpret_cast<bf16x4*>(d + i) = o;
}

// ---------------- GEMM: Y[m,n] = sum_k A[m,k] * B[n,k]  (B^T layout) ----------------
template <int MODE>
__global__ __launch_bounds__(256)
void gemm_bt(const bf16_t* __restrict__ A,
             const bf16_t* __restrict__ B0,
             const bf16_t* __restrict__ B1,
             const bf16_t* __restrict__ B2,
             bf16_t* __restrict__ outQ,
             bf16_t* __restrict__ outK,
             bf16_t* __restrict__ outVt,
             float* __restrict__ outF) {
    __shared__ bf16_t As[128 * 32];
    __shared__ bf16_t Bs[128 * 32];

    const int t = threadIdx.x;
    const int z = blockIdx.z;
    const bf16_t* Bm = (MODE == 0) ? (z == 0 ? B0 : (z == 1 ? B1 : B2)) : B0;

    const int m0 = blockIdx.x * 128;
    const int n0 = blockIdx.y * 128;
    const int lane = t & 63;
    const int w = t >> 6;
    const int wr = w >> 1;
    const int wc = w & 1;

    f32x4 acc[4][4] = {};

    const int ar = t >> 2;
    const int ac = (t & 3) * 8;
    const bf16_t* Ag = A + (size_t)m0 * KDIM;
    const bf16_t* Bg = Bm + (size_t)n0 * KDIM;

    const int rr = lane & 15;
    const int ko = (lane >> 4) * 8;

    for (int k0 = 0; k0 < KDIM; k0 += 32) {
        gload_lds16(Ag + (size_t)ar * KDIM + k0 + ac,        &As[t * 8]);
        gload_lds16(Ag + (size_t)(ar + 64) * KDIM + k0 + ac, &As[2048 + t * 8]);
        gload_lds16(Bg + (size_t)ar * KDIM + k0 + ac,        &Bs[t * 8]);
        gload_lds16(Bg + (size_t)(ar + 64) * KDIM + k0 + ac, &Bs[2048 + t * 8]);
        __syncthreads();

        bf16x8 af[4], bfr[4];
#pragma unroll
        for (int m = 0; m < 4; ++m)
            af[m] = *reinterpret_cast<const bf16x8*>(&As[(wr * 64 + m * 16 + rr) * 32 + ko]);
#pragma unroll
        for (int n = 0; n < 4; ++n)
            bfr[n] = *reinterpret_cast<const bf16x8*>(&Bs[(wc * 64 + n * 16 + rr) * 32 + ko]);
#pragma unroll
        for (int m = 0; m < 4; ++m)
#pragma unroll
            for (int n = 0; n < 4; ++n)
                acc[m][n] = MFMA(af[m], bfr[n], acc[m][n]);
        __syncthreads();
    }

    const int rbase = m0 + wr * 64 + (lane >> 4) * 4;
    const int cbase = n0 + wc * 64 + (lane & 15);
#pragma unroll
    for (int m = 0; m < 4; ++m) {
#pragma unroll
        for (int n = 0; n < 4; ++n) {
            const int gn = cbase + n * 16;
            if (MODE == 0) {
                const int h = gn >> 6, d = gn & 63;
                if (z < 2) {
                    bf16_t* dst = (z == 0) ? outQ : outK;
#pragma unroll
                    for (int j = 0; j < 4; ++j) {
                        const int gm = rbase + m * 16 + j;
                        const int b = gm >> 11, s = gm & (S_DIM - 1);
                        dst[(((size_t)(b * H_DIM + h) * S_DIM + s) << 6) + d] = (__bf16)acc[m][n][j];
                    }
                } else {
                    bf16x4 v;
#pragma unroll
                    for (int j = 0; j < 4; ++j) v[j] = (__bf16)acc[m][n][j];
                    const int gm = rbase + m * 16;
                    const int b = gm >> 11, s = gm & (S_DIM - 1);
                    *reinterpret_cast<bf16x4*>(
                        &outVt[((size_t)(b * H_DIM + h) * DK + d) * S_DIM + s]) = v;
                }
            } else {
#pragma unroll
                for (int j = 0; j < 4; ++j) {
                    const int gm = rbase + m * 16 + j;
                    outF[(size_t)gm * DM + gn] = acc[m][n][j];
                }
            }
        }
    }
}

// ---------------- RoPE (in-place on Q and K, [B,H,S,64] bf16) ----------------
__global__ void rope_kernel(bf16_t* __restrict__ Q, bf16_t* __restrict__ Kb,
                            const int* __restrict__ pos, int total) {
    int idx = blockIdx.x * blockDim.x + threadIdx.x;
    if (idx >= total) return;
    const int j = idx & 31;
    const int s = (idx >> 5) & (S_DIM - 1);
    const float p = (float)pos[s];
    const float freq = exp2f((float)j * (-13.287712379549449f / 32.0f));
    const float ang = p * freq;
    const float sn = sinf(ang), cs = cosf(ang);
    const size_t base = ((size_t)(idx >> 5) << 6) + (size_t)(j * 2);
    const float q1 = (float)Q[base], q2 = (float)Q[base + 1];
    Q[base]     = (__bf16)(q1 * cs - q2 * sn);
    Q[base + 1] = (__bf16)(q1 * sn + q2 * cs);
    const float k1 = (float)Kb[base], k2 = (float)Kb[base + 1];
    Kb[base]     = (__bf16)(k1 * cs - k2 * sn);
    Kb[base + 1] = (__bf16)(k1 * sn + k2 * cs);
}

// ---------------- causal flash attention v5 ----------------
// Block = 4 waves = one 64-row q-block. K tiles LDS-shared (2-buf, XOR-swizzled,
// counted vmcnt, one barrier/tile). V tiles -> PRIVATE REGS via exact inline-asm
// loads issued at iter top, consumed after softmax (latency hidden; no V LDS).
// Shuffle-free steady-state softmax: lane-local defer-max trip check, deferred
// l reduction. Swapped QK^T (lane owns one q-row); PV: O^T = mfma(V, P).
__global__ __launch_bounds__(256, 4)
void attn_kernel(const bf16_t* __restrict__ Q, const bf16_t* __restrict__ Kg,
                 const bf16_t* __restrict__ Vt, bf16_t* __restrict__ O) {
    constexpr int PSTR = 72;
    __shared__ bf16_t Ks[2][64 * 64];
    __shared__ bf16_t P_lds[4][16 * PSTR];

    const int t = threadIdx.x;
    const int lane = t & 63;
    const int w = t >> 6;
    constexpr int nQ = S_DIM / 64;  // 32 q-blocks
    const int bh = blockIdx.x / nQ;
    const int qi = blockIdx.x % nQ;
    const int qb = nQ - 1 - qi;     // heavy blocks first
    const int q0w = qb * 64 + w * 16;
    const int b = bh >> 4, h = bh & 15;
    const int rr = lane & 15;
    const int hi = lane >> 4;

    const bf16_t* Qp  = Q  + ((size_t)bh * S_DIM + q0w) * DK;
    const bf16_t* Kbh = Kg + (size_t)bh * S_DIM * DK;
    const bf16_t* Vbh = Vt + (size_t)bh * DK * S_DIM;   // [d][s]
    bf16_t* Pw = P_lds[w];

    // K staging: 512 x 16B chunks; thread t does chunks t and t+256.
    // LDS dest linear; global source pre-swizzled: col ^= (row&7)*8 elems.
    const int i0 = t, i1 = t + 256;
    const int r0 = i0 >> 3, c0 = ((i0 & 7) ^ (r0 & 7)) * 8;
    const int r1 = i1 >> 3, c1 = ((i1 & 7) ^ (r1 & 7)) * 8;

    // Q fragments (B-operand), fold 1/8 exactly
    bf16x8 qf[2];
    qf[0] = *reinterpret_cast<const bf16x8*>(&Qp[rr * DK + hi * 8]);
    qf[1] = *reinterpret_cast<const bf16x8*>(&Qp[rr * DK + 32 + hi * 8]);
#pragma unroll
    for (int i = 0; i < 8; ++i) {
        qf[0][i] = (__bf16)((float)qf[0][i] * 0.125f);
        qf[1][i] = (__bf16)((float)qf[1][i] * 0.125f);
    }

    f32x4 o[4] = {};
    float m = -INFINITY, lpart = 0.0f;
    const float L2E = 1.4426950408889634f;

    const int nt = qb + 1;  // 64-kv tiles

    // prologue: K(0) -> Ks[0]  (2 vmem events)
    gload_lds16(Kbh + (size_t)r0 * DK + c0, &Ks[0][i0 * 8]);
    gload_lds16(Kbh + (size_t)r1 * DK + c1, &Ks[0][i1 * 8]);

    for (int tt = 0; tt < nt; ++tt) {
        const int kv0 = tt * 64;

        // [1] V(t) -> regs: exactly 8 dwordx4, issued first, consumed after softmax
        i32x4 vraw[4][2];
#pragma unroll
        for (int db = 0; db < 4; ++db) {
            const bf16_t* Vr = Vbh + (size_t)(db * 16 + rr) * S_DIM + kv0;
            vraw[db][0] = gload_b128(Vr + hi * 8);
            vraw[db][1] = gload_b128(Vr + 32 + hi * 8);
        }
        __builtin_amdgcn_sched_barrier(0);
        // [3] own K(t) landed (outstanding: 8 V loads may fly)
        asm volatile("s_waitcnt vmcnt(8)" ::: "memory");
        __builtin_amdgcn_s_barrier();   // all waves' K(t) landed
        __builtin_amdgcn_sched_barrier(0);

        // [5] QK^T from Ks[tt&1]: s[t16][j] = S[kv = t16*16+hi*4+j][q = rr]
        const bf16_t* Kc = Ks[tt & 1];
        f32x4 s[4] = {};
        __builtin_amdgcn_s_setprio(1);
#pragma unroll
        for (int t16 = 0; t16 < 4; ++t16) {
            const int r = t16 * 16 + rr;
            const int sw = (r & 7) * 8;
            bf16x8 kf0 = *reinterpret_cast<const bf16x8*>(&Kc[r * 64 + ((hi * 8) ^ sw)]);
            bf16x8 kf1 = *reinterpret_cast<const bf16x8*>(&Kc[r * 64 + ((32 + hi * 8) ^ sw)]);
            s[t16] = MFMA(kf0, qf[0], s[t16]);
            s[t16] = MFMA(kf1, qf[1], s[t16]);
        }
        __builtin_amdgcn_s_setprio(0);
        __builtin_amdgcn_sched_barrier(0);
        // [2'] K(t+1) -> other buffer (safe: all waves are past barrier(t))
        if (tt + 1 < nt) {
            const int kv1 = (tt + 1) * 64;
            bf16_t* Kn = Ks[(tt + 1) & 1];
            gload_lds16(Kbh + (size_t)(kv1 + r0) * DK + c0, &Kn[i0 * 8]);
            gload_lds16(Kbh + (size_t)(kv1 + r1) * DK + c1, &Kn[i1 * 8]);
        }
        __builtin_amdgcn_sched_barrier(0);

        // causal mask — only the last tile touches the diagonal
        if (tt == nt - 1) {
            const int qg = q0w + rr;
#pragma unroll
            for (int t16 = 0; t16 < 4; ++t16)
#pragma unroll
                for (int j = 0; j < 4; ++j)
                    if (kv0 + t16 * 16 + hi * 4 + j > qg) s[t16][j] = -INFINITY;
        }

        // lane-local max; shuffle-free trip check (defer-max, THR=8)
        float mloc = s[0][0];
#pragma unroll
        for (int t16 = 0; t16 < 4; ++t16)
#pragma unroll
            for (int j = 0; j < 4; ++j) mloc = fmaxf(mloc, s[t16][j]);
        if (__any(mloc - m > 8.0f)) {      // rare after first tile
            float mf = fmaxf(mloc, __shfl_xor(mloc, 16));
            mf = fmaxf(mf, __shfl_xor(mf, 32));
            const float mnew = fmaxf(m, mf);
            const float scale = exp2f((m - mnew) * L2E);
            lpart *= scale;
#pragma unroll
            for (int db = 0; db < 4; ++db)
#pragma unroll
                for (int j = 0; j < 4; ++j) o[db][j] *= scale;
            m = mnew;
        }

        // P = exp(s - m); per-lane partial l (cross-lane reduce deferred to end)
        float psum = 0.0f;
#pragma unroll
        for (int t16 = 0; t16 < 4; ++t16) {
            bf16x4 pb;
#pragma unroll
            for (int j = 0; j < 4; ++j) {
                const float p = exp2f((s[t16][j] - m) * L2E);
                psum += p;
                pb[j] = (__bf16)p;
            }
            *reinterpret_cast<bf16x4*>(&Pw[rr * PSTR + t16 * 16 + hi * 4]) = pb;
        }
        lpart += psum;

        // P fragments for PV (per-wave LDS slice, no barrier)
        bf16x8 pf0 = *reinterpret_cast<const bf16x8*>(&Pw[rr * PSTR + hi * 8]);
        bf16x8 pf1 = *reinterpret_cast<const bf16x8*>(&Pw[rr * PSTR + 32 + hi * 8]);

        // [6] V(t) regs valid (K(t+1) may stay in flight)
        if (tt + 1 < nt) { asm volatile("s_waitcnt vmcnt(2)" ::: "memory"); }
        else             { asm volatile("s_waitcnt vmcnt(0)" ::: "memory"); }
        __builtin_amdgcn_sched_barrier(0);

        // [7] PV: O^T[d][q] += V[d][kv] * P[q][kv]
        __builtin_amdgcn_s_setprio(1);
#pragma unroll
        for (int db = 0; db < 4; ++db) {
            const bf16x8 vf0 = *reinterpret_cast<const bf16x8*>(&vraw[db][0]);
            const bf16x8 vf1 = *reinterpret_cast<const bf16x8*>(&vraw[db][1]);
            o[db] = MFMA(vf0, pf0, o[db]);
            o[db] = MFMA(vf1, pf1, o[db]);
        }
        __builtin_amdgcn_s_setprio(0);
    }

    // deferred l reduction (once)
    float lsum = lpart;
    lsum += __shfl_xor(lsum, 16);
    lsum += __shfl_xor(lsum, 32);
    const float linv = 1.0f / lsum;
#pragma unroll
    for (int db = 0; db < 4; ++db) {
        bf16x4 ov;
#pragma unroll
        for (int j = 0; j < 4; ++j) ov[j] = (__bf16)(o[db][j] * linv);
        *reinterpret_cast<bf16x4*>(
            &O[((size_t)(b * S_DIM + q0w + rr)) * DM + h * DK + db * 16 + hi * 4]) = ov;
    }
}

extern "C" void kernel_launch(void* const* d_in, const int* in_sizes, int n_in,
                              void* d_out, int out_size, void* d_ws, size_t ws_size,
                              hipStream_t stream) {
    const float* x  = (const float*)d_in[0];
    const float* Wq = (const float*)d_in[1];
    const float* Wk = (const float*)d_in[2];
    const float* Wv = (const float*)d_in[3];
    const float* Wo = (const float*)d_in[4];
    const int* pos  = (const int*)d_in[5];
    float* out = (float*)d_out;

    char* ws = (char*)d_ws;
    bf16_t* xb  = (bf16_t*)(ws);
    bf16_t* Wqb = (bf16_t*)(ws + (8u << 20));
    bf16_t* Wkb = (bf16_t*)(ws + (10u << 20));
    bf16_t* Wvb = (bf16_t*)(ws + (12u << 20));
    bf16_t* Wob = (bf16_t*)(ws + (14u << 20));
    bf16_t* Qb  = (bf16_t*)(ws + (16u << 20));
    bf16_t* Kb  = (bf16_t*)(ws + (24u << 20));
    bf16_t* Vtb = (bf16_t*)(ws + (32u << 20));
    bf16_t* Ab  = (bf16_t*)(ws);  // reuse xb region after QKV GEMM

    const int NX = B_DIM * S_DIM * DM;
    const int NW = DM * DM;

    cvt_kernel<<<NX / 1024, 256, 0, stream>>>(x, xb, NX);
    cvt4_kernel<<<dim3(NW / 1024, 4), 256, 0, stream>>>(Wq, Wk, Wv, Wo,
                                                        Wqb, Wkb, Wvb, Wob, NW);

    gemm_bt<0><<<dim3(32, 8, 3), 256, 0, stream>>>(xb, Wqb, Wkb, Wvb, Qb, Kb, Vtb, nullptr);

    const int total_pairs = B_DIM * H_DIM * S_DIM * 32;
    rope_kernel<<<total_pairs / 256, 256, 0, stream>>>(Qb, Kb, pos, total_pairs);

    attn_kernel<<<B_DIM * H_DIM * (S_DIM / 64), 256, 0, stream>>>(Qb, Kb, Vtb, Ab);

    gemm_bt<1><<<dim3(32, 8, 1), 256, 0, stream>>>(Ab, Wob, nullptr, nullptr,
                                                   nullptr, nullptr, nullptr, out);
}

// Round 6
// 141.390 us; speedup vs baseline: 1.4535x; 1.4535x over previous
//
#include <hip/hip_runtime.h>
#include <hip/hip_bf16.h>
#include <math.h>

typedef __bf16 bf16_t;
typedef __attribute__((ext_vector_type(8))) __bf16 bf16x8;
typedef __attribute__((ext_vector_type(4))) __bf16 bf16x4;
typedef __attribute__((ext_vector_type(4))) float f32x4;

#define B_DIM 2
#define S_DIM 2048
#define H_DIM 16
#define DK 64
#define DM 1024
#define KDIM 1024

#define MFMA(a, b, c) __builtin_amdgcn_mfma_f32_16x16x32_bf16((a), (b), (c), 0, 0, 0)

__device__ __forceinline__ void gload_lds16(const bf16_t* g, bf16_t* l) {
    __builtin_amdgcn_global_load_lds(
        (const __attribute__((address_space(1))) void*)g,
        (__attribute__((address_space(3))) void*)l, 16, 0, 0);
}

// ---------------- fp32 -> bf16 convert ----------------
__global__ void cvt_kernel(const float* __restrict__ src, bf16_t* __restrict__ dst, int n) {
    int i = (blockIdx.x * blockDim.x + threadIdx.x) * 4;
    if (i >= n) return;
    float4 v = *reinterpret_cast<const float4*>(src + i);
    bf16x4 o;
    o[0] = (__bf16)v.x; o[1] = (__bf16)v.y; o[2] = (__bf16)v.z; o[3] = (__bf16)v.w;
    *reinterpret_cast<bf16x4*>(dst + i) = o;
}

__global__ void cvt4_kernel(const float* __restrict__ s0, const float* __restrict__ s1,
                            const float* __restrict__ s2, const float* __restrict__ s3,
                            bf16_t* __restrict__ d0, bf16_t* __restrict__ d1,
                            bf16_t* __restrict__ d2, bf16_t* __restrict__ d3, int n) {
    const float* s; bf16_t* d;
    switch (blockIdx.y) {
        case 0: s = s0; d = d0; break;
        case 1: s = s1; d = d1; break;
        case 2: s = s2; d = d2; break;
        default: s = s3; d = d3; break;
    }
    int i = (blockIdx.x * blockDim.x + threadIdx.x) * 4;
    if (i >= n) return;
    float4 v = *reinterpret_cast<const float4*>(s + i);
    bf16x4 o;
    o[0] = (__bf16)v.x; o[1] = (__bf16)v.y; o[2] = (__bf16)v.z; o[3] = (__bf16)v.w;
    *reinterpret_cast<bf16x4*>(d + i) = o;
}

// ---------------- GEMM: Y[m,n] = sum_k A[m,k] * B[n,k]  (B^T layout) ----------------
template <int MODE>
__global__ __launch_bounds__(256)
void gemm_bt(const bf16_t* __restrict__ A,
             const bf16_t* __restrict__ B0,
             const bf16_t* __restrict__ B1,
             const bf16_t* __restrict__ B2,
             bf16_t* __restrict__ outQ,
             bf16_t* __restrict__ outK,
             bf16_t* __restrict__ outVt,
             float* __restrict__ outF) {
    __shared__ bf16_t As[128 * 32];
    __shared__ bf16_t Bs[128 * 32];

    const int t = threadIdx.x;
    const int z = blockIdx.z;
    const bf16_t* Bm = (MODE == 0) ? (z == 0 ? B0 : (z == 1 ? B1 : B2)) : B0;

    const int m0 = blockIdx.x * 128;
    const int n0 = blockIdx.y * 128;
    const int lane = t & 63;
    const int w = t >> 6;
    const int wr = w >> 1;
    const int wc = w & 1;

    f32x4 acc[4][4] = {};

    const int ar = t >> 2;
    const int ac = (t & 3) * 8;
    const bf16_t* Ag = A + (size_t)m0 * KDIM;
    const bf16_t* Bg = Bm + (size_t)n0 * KDIM;

    const int rr = lane & 15;
    const int ko = (lane >> 4) * 8;

    for (int k0 = 0; k0 < KDIM; k0 += 32) {
        gload_lds16(Ag + (size_t)ar * KDIM + k0 + ac,        &As[t * 8]);
        gload_lds16(Ag + (size_t)(ar + 64) * KDIM + k0 + ac, &As[2048 + t * 8]);
        gload_lds16(Bg + (size_t)ar * KDIM + k0 + ac,        &Bs[t * 8]);
        gload_lds16(Bg + (size_t)(ar + 64) * KDIM + k0 + ac, &Bs[2048 + t * 8]);
        __syncthreads();

        bf16x8 af[4], bfr[4];
#pragma unroll
        for (int m = 0; m < 4; ++m)
            af[m] = *reinterpret_cast<const bf16x8*>(&As[(wr * 64 + m * 16 + rr) * 32 + ko]);
#pragma unroll
        for (int n = 0; n < 4; ++n)
            bfr[n] = *reinterpret_cast<const bf16x8*>(&Bs[(wc * 64 + n * 16 + rr) * 32 + ko]);
#pragma unroll
        for (int m = 0; m < 4; ++m)
#pragma unroll
            for (int n = 0; n < 4; ++n)
                acc[m][n] = MFMA(af[m], bfr[n], acc[m][n]);
        __syncthreads();
    }

    const int rbase = m0 + wr * 64 + (lane >> 4) * 4;
    const int cbase = n0 + wc * 64 + (lane & 15);
#pragma unroll
    for (int m = 0; m < 4; ++m) {
#pragma unroll
        for (int n = 0; n < 4; ++n) {
            const int gn = cbase + n * 16;
            if (MODE == 0) {
                const int h = gn >> 6, d = gn & 63;
                if (z < 2) {
                    bf16_t* dst = (z == 0) ? outQ : outK;
#pragma unroll
                    for (int j = 0; j < 4; ++j) {
                        const int gm = rbase + m * 16 + j;
                        const int b = gm >> 11, s = gm & (S_DIM - 1);
                        dst[(((size_t)(b * H_DIM + h) * S_DIM + s) << 6) + d] = (__bf16)acc[m][n][j];
                    }
                } else {
                    bf16x4 v;
#pragma unroll
                    for (int j = 0; j < 4; ++j) v[j] = (__bf16)acc[m][n][j];
                    const int gm = rbase + m * 16;
                    const int b = gm >> 11, s = gm & (S_DIM - 1);
                    *reinterpret_cast<bf16x4*>(
                        &outVt[((size_t)(b * H_DIM + h) * DK + d) * S_DIM + s]) = v;
                }
            } else {
#pragma unroll
                for (int j = 0; j < 4; ++j) {
                    const int gm = rbase + m * 16 + j;
                    outF[(size_t)gm * DM + gn] = acc[m][n][j];
                }
            }
        }
    }
}

// ---------------- RoPE (in-place on Q and K, [B,H,S,64] bf16) ----------------
__global__ void rope_kernel(bf16_t* __restrict__ Q, bf16_t* __restrict__ Kb,
                            const int* __restrict__ pos, int total) {
    int idx = blockIdx.x * blockDim.x + threadIdx.x;
    if (idx >= total) return;
    const int j = idx & 31;
    const int s = (idx >> 5) & (S_DIM - 1);
    const float p = (float)pos[s];
    const float freq = exp2f((float)j * (-13.287712379549449f / 32.0f));
    const float ang = p * freq;
    const float sn = sinf(ang), cs = cosf(ang);
    const size_t base = ((size_t)(idx >> 5) << 6) + (size_t)(j * 2);
    const float q1 = (float)Q[base], q2 = (float)Q[base + 1];
    Q[base]     = (__bf16)(q1 * cs - q2 * sn);
    Q[base + 1] = (__bf16)(q1 * sn + q2 * cs);
    const float k1 = (float)Kb[base], k2 = (float)Kb[base + 1];
    Kb[base]     = (__bf16)(k1 * cs - k2 * sn);
    Kb[base + 1] = (__bf16)(k1 * sn + k2 * cs);
}

// ---------------- causal flash attention v6: paired q-blocks ----------------
// Block = 4 waves, owns q-blocks qbH = 31-qi and qbL = qi (uniform 33 tile-
// chains/block -> 512 identical blocks, 2/CU resident, no imbalance tail).
// In the dual region (tt <= qbL) each wave runs TWO independent chains off the
// same K/V LDS tile (shared K-fragment reads) -> intra-wave ILP fills stalls.
// K/V double-buffered LDS (XOR-swizzled, gload_lds staged at loop top).
__global__ __launch_bounds__(256)
void attn_kernel(const bf16_t* __restrict__ Q, const bf16_t* __restrict__ Kg,
                 const bf16_t* __restrict__ Vt, bf16_t* __restrict__ O) {
    constexpr int PSTR = 72;
    __shared__ bf16_t Ks[2][64 * 64];
    __shared__ bf16_t Vs[2][64 * 64];
    __shared__ bf16_t P_lds[4][2][16 * PSTR];

    const int t = threadIdx.x;
    const int lane = t & 63;
    const int w = t >> 6;
    const int bh = blockIdx.x >> 4;   // 32 (b,h)
    const int qi = blockIdx.x & 15;
    const int qbH = 31 - qi, qbL = qi;
    const int q0H = qbH * 64 + w * 16;
    const int q0L = qbL * 64 + w * 16;
    const int b = bh >> 4, h = bh & 15;
    const int rr = lane & 15;
    const int hi = lane >> 4;

    const bf16_t* Kbh = Kg + (size_t)bh * S_DIM * DK;
    const bf16_t* Vbh = Vt + (size_t)bh * DK * S_DIM;   // [d][s]
    bf16_t* PwH = P_lds[w][0];
    bf16_t* PwL = P_lds[w][1];

    // staging: 512 x 16B chunks per 8KB tile; thread t does chunks t and t+256.
    // LDS dest linear; global source pre-swizzled: col ^= (row&7)*8 elems.
    const int i0 = t, i1 = t + 256;
    const int r0 = i0 >> 3, c0 = ((i0 & 7) ^ (r0 & 7)) * 8;
    const int r1 = i1 >> 3, c1 = ((i1 & 7) ^ (r1 & 7)) * 8;

    // Q fragments for both chains (B-operand), fold 1/8 exactly
    const bf16_t* QpH = Q + ((size_t)bh * S_DIM + q0H) * DK;
    const bf16_t* QpL = Q + ((size_t)bh * S_DIM + q0L) * DK;
    bf16x8 qfH[2], qfL[2];
    qfH[0] = *reinterpret_cast<const bf16x8*>(&QpH[rr * DK + hi * 8]);
    qfH[1] = *reinterpret_cast<const bf16x8*>(&QpH[rr * DK + 32 + hi * 8]);
    qfL[0] = *reinterpret_cast<const bf16x8*>(&QpL[rr * DK + hi * 8]);
    qfL[1] = *reinterpret_cast<const bf16x8*>(&QpL[rr * DK + 32 + hi * 8]);
#pragma unroll
    for (int i = 0; i < 8; ++i) {
        qfH[0][i] = (__bf16)((float)qfH[0][i] * 0.125f);
        qfH[1][i] = (__bf16)((float)qfH[1][i] * 0.125f);
        qfL[0][i] = (__bf16)((float)qfL[0][i] * 0.125f);
        qfL[1][i] = (__bf16)((float)qfL[1][i] * 0.125f);
    }

    f32x4 oH[4] = {}, oL[4] = {};
    float mH = -INFINITY, lH = 0.0f, mL = -INFINITY, lL = 0.0f;
    const float L2E = 1.4426950408889634f;

    const int ntH = qbH + 1;

    // prologue: stage tile 0 into buf 0
    gload_lds16(Kbh + (size_t)r0 * DK + c0, &Ks[0][i0 * 8]);
    gload_lds16(Kbh + (size_t)r1 * DK + c1, &Ks[0][i1 * 8]);
    gload_lds16(Vbh + (size_t)r0 * S_DIM + c0, &Vs[0][i0 * 8]);
    gload_lds16(Vbh + (size_t)r1 * S_DIM + c1, &Vs[0][i1 * 8]);
    __syncthreads();

    for (int tt = 0; tt < ntH; ++tt) {
        const int cur = tt & 1;
        const int kv0 = tt * 64;
        const bool doL = (tt <= qbL);

        // stage next tile (other buffer); post-barrier => 2 buffers are safe
        if (tt + 1 < ntH) {
            const int kv1 = kv0 + 64;
            bf16_t* Kn = Ks[cur ^ 1];
            bf16_t* Vn = Vs[cur ^ 1];
            gload_lds16(Kbh + (size_t)(kv1 + r0) * DK + c0, &Kn[i0 * 8]);
            gload_lds16(Kbh + (size_t)(kv1 + r1) * DK + c1, &Kn[i1 * 8]);
            gload_lds16(Vbh + (size_t)r0 * S_DIM + kv1 + c0, &Vn[i0 * 8]);
            gload_lds16(Vbh + (size_t)r1 * S_DIM + kv1 + c1, &Vn[i1 * 8]);
        }
        const bf16_t* Kc = Ks[cur];
        const bf16_t* Vc = Vs[cur];

        // QK^T, both chains sharing K fragments: s*[t16][j] = S[kv][q=rr]
        f32x4 sH[4] = {}, sL[4] = {};
        __builtin_amdgcn_s_setprio(1);
#pragma unroll
        for (int t16 = 0; t16 < 4; ++t16) {
            const int r = t16 * 16 + rr;
            const int sw = (r & 7) * 8;
            bf16x8 kf0 = *reinterpret_cast<const bf16x8*>(&Kc[r * 64 + ((hi * 8) ^ sw)]);
            bf16x8 kf1 = *reinterpret_cast<const bf16x8*>(&Kc[r * 64 + ((32 + hi * 8) ^ sw)]);
            sH[t16] = MFMA(kf0, qfH[0], sH[t16]);
            sH[t16] = MFMA(kf1, qfH[1], sH[t16]);
            if (doL) {
                sL[t16] = MFMA(kf0, qfL[0], sL[t16]);
                sL[t16] = MFMA(kf1, qfL[1], sL[t16]);
            }
        }
        __builtin_amdgcn_s_setprio(0);

        // causal masks — only each chain's diagonal tile
        if (tt == qbH) {
            const int qg = q0H + rr;
#pragma unroll
            for (int t16 = 0; t16 < 4; ++t16)
#pragma unroll
                for (int j = 0; j < 4; ++j)
                    if (kv0 + t16 * 16 + hi * 4 + j > qg) sH[t16][j] = -INFINITY;
        }
        if (tt == qbL) {
            const int qg = q0L + rr;
#pragma unroll
            for (int t16 = 0; t16 < 4; ++t16)
#pragma unroll
                for (int j = 0; j < 4; ++j)
                    if (kv0 + t16 * 16 + hi * 4 + j > qg) sL[t16][j] = -INFINITY;
        }

        // ---- softmax H (lane-local defer-max trip, THR=8) ----
        {
            float mloc = sH[0][0];
#pragma unroll
            for (int t16 = 0; t16 < 4; ++t16)
#pragma unroll
                for (int j = 0; j < 4; ++j) mloc = fmaxf(mloc, sH[t16][j]);
            if (__any(mloc - mH > 8.0f)) {
                float mf = fmaxf(mloc, __shfl_xor(mloc, 16));
                mf = fmaxf(mf, __shfl_xor(mf, 32));
                const float mnew = fmaxf(mH, mf);
                const float scale = exp2f((mH - mnew) * L2E);
                lH *= scale;
#pragma unroll
                for (int db = 0; db < 4; ++db)
#pragma unroll
                    for (int j = 0; j < 4; ++j) oH[db][j] *= scale;
                mH = mnew;
            }
            float psum = 0.0f;
#pragma unroll
            for (int t16 = 0; t16 < 4; ++t16) {
                bf16x4 pb;
#pragma unroll
                for (int j = 0; j < 4; ++j) {
                    const float p = exp2f((sH[t16][j] - mH) * L2E);
                    psum += p;
                    pb[j] = (__bf16)p;
                }
                *reinterpret_cast<bf16x4*>(&PwH[rr * PSTR + t16 * 16 + hi * 4]) = pb;
            }
            lH += psum;
        }
        // ---- softmax L ----
        if (doL) {
            float mloc = sL[0][0];
#pragma unroll
            for (int t16 = 0; t16 < 4; ++t16)
#pragma unroll
                for (int j = 0; j < 4; ++j) mloc = fmaxf(mloc, sL[t16][j]);
            if (__any(mloc - mL > 8.0f)) {
                float mf = fmaxf(mloc, __shfl_xor(mloc, 16));
                mf = fmaxf(mf, __shfl_xor(mf, 32));
                const float mnew = fmaxf(mL, mf);
                const float scale = exp2f((mL - mnew) * L2E);
                lL *= scale;
#pragma unroll
                for (int db = 0; db < 4; ++db)
#pragma unroll
                    for (int j = 0; j < 4; ++j) oL[db][j] *= scale;
                mL = mnew;
            }
            float psum = 0.0f;
#pragma unroll
            for (int t16 = 0; t16 < 4; ++t16) {
                bf16x4 pb;
#pragma unroll
                for (int j = 0; j < 4; ++j) {
                    const float p = exp2f((sL[t16][j] - mL) * L2E);
                    psum += p;
                    pb[j] = (__bf16)p;
                }
                *reinterpret_cast<bf16x4*>(&PwL[rr * PSTR + t16 * 16 + hi * 4]) = pb;
            }
            lL += psum;
        }

        // ---- PV, both chains sharing V fragments ----
        bf16x8 pH0 = *reinterpret_cast<const bf16x8*>(&PwH[rr * PSTR + hi * 8]);
        bf16x8 pH1 = *reinterpret_cast<const bf16x8*>(&PwH[rr * PSTR + 32 + hi * 8]);
        bf16x8 pL0, pL1;
        if (doL) {
            pL0 = *reinterpret_cast<const bf16x8*>(&PwL[rr * PSTR + hi * 8]);
            pL1 = *reinterpret_cast<const bf16x8*>(&PwL[rr * PSTR + 32 + hi * 8]);
        }
        __builtin_amdgcn_s_setprio(1);
#pragma unroll
        for (int db = 0; db < 4; ++db) {
            const int vr = db * 16 + rr;
            const int sw = (vr & 7) * 8;
            bf16x8 vf0 = *reinterpret_cast<const bf16x8*>(&Vc[vr * 64 + ((hi * 8) ^ sw)]);
            bf16x8 vf1 = *reinterpret_cast<const bf16x8*>(&Vc[vr * 64 + ((32 + hi * 8) ^ sw)]);
            oH[db] = MFMA(vf0, pH0, oH[db]);
            oH[db] = MFMA(vf1, pH1, oH[db]);
            if (doL) {
                oL[db] = MFMA(vf0, pL0, oL[db]);
                oL[db] = MFMA(vf1, pL1, oL[db]);
            }
        }
        __builtin_amdgcn_s_setprio(0);

        __syncthreads();   // drains staged loads; separates buffer reuse
    }

    // epilogue: both chains (l-reduce deferred to once)
    {
        float ls = lH;
        ls += __shfl_xor(ls, 16);
        ls += __shfl_xor(ls, 32);
        const float linv = 1.0f / ls;
#pragma unroll
        for (int db = 0; db < 4; ++db) {
            bf16x4 ov;
#pragma unroll
            for (int j = 0; j < 4; ++j) ov[j] = (__bf16)(oH[db][j] * linv);
            *reinterpret_cast<bf16x4*>(
                &O[((size_t)(b * S_DIM + q0H + rr)) * DM + h * DK + db * 16 + hi * 4]) = ov;
        }
    }
    {
        float ls = lL;
        ls += __shfl_xor(ls, 16);
        ls += __shfl_xor(ls, 32);
        const float linv = 1.0f / ls;
#pragma unroll
        for (int db = 0; db < 4; ++db) {
            bf16x4 ov;
#pragma unroll
            for (int j = 0; j < 4; ++j) ov[j] = (__bf16)(oL[db][j] * linv);
            *reinterpret_cast<bf16x4*>(
                &O[((size_t)(b * S_DIM + q0L + rr)) * DM + h * DK + db * 16 + hi * 4]) = ov;
        }
    }
}

extern "C" void kernel_launch(void* const* d_in, const int* in_sizes, int n_in,
                              void* d_out, int out_size, void* d_ws, size_t ws_size,
                              hipStream_t stream) {
    const float* x  = (const float*)d_in[0];
    const float* Wq = (const float*)d_in[1];
    const float* Wk = (const float*)d_in[2];
    const float* Wv = (const float*)d_in[3];
    const float* Wo = (const float*)d_in[4];
    const int* pos  = (const int*)d_in[5];
    float* out = (float*)d_out;

    char* ws = (char*)d_ws;
    bf16_t* xb  = (bf16_t*)(ws);
    bf16_t* Wqb = (bf16_t*)(ws + (8u << 20));
    bf16_t* Wkb = (bf16_t*)(ws + (10u << 20));
    bf16_t* Wvb = (bf16_t*)(ws + (12u << 20));
    bf16_t* Wob = (bf16_t*)(ws + (14u << 20));
    bf16_t* Qb  = (bf16_t*)(ws + (16u << 20));
    bf16_t* Kb  = (bf16_t*)(ws + (24u << 20));
    bf16_t* Vtb = (bf16_t*)(ws + (32u << 20));
    bf16_t* Ab  = (bf16_t*)(ws);  // reuse xb region after QKV GEMM

    const int NX = B_DIM * S_DIM * DM;
    const int NW = DM * DM;

    cvt_kernel<<<NX / 1024, 256, 0, stream>>>(x, xb, NX);
    cvt4_kernel<<<dim3(NW / 1024, 4), 256, 0, stream>>>(Wq, Wk, Wv, Wo,
                                                        Wqb, Wkb, Wvb, Wob, NW);

    gemm_bt<0><<<dim3(32, 8, 3), 256, 0, stream>>>(xb, Wqb, Wkb, Wvb, Qb, Kb, Vtb, nullptr);

    const int total_pairs = B_DIM * H_DIM * S_DIM * 32;
    rope_kernel<<<total_pairs / 256, 256, 0, stream>>>(Qb, Kb, pos, total_pairs);

    attn_kernel<<<B_DIM * H_DIM * 16, 256, 0, stream>>>(Qb, Kb, Vtb, Ab);

    gemm_bt<1><<<dim3(32, 8, 1), 256, 0, stream>>>(Ab, Wob, nullptr, nullptr,
                                                   nullptr, nullptr, nullptr, out);
}

// Round 7
// 141.184 us; speedup vs baseline: 1.4556x; 1.0015x over previous
//
#include <hip/hip_runtime.h>
#include <hip/hip_bf16.h>
#include <math.h>

typedef __bf16 bf16_t;
typedef __attribute__((ext_vector_type(8))) __bf16 bf16x8;
typedef __attribute__((ext_vector_type(4))) __bf16 bf16x4;
typedef __attribute__((ext_vector_type(4))) float f32x4;

#define B_DIM 2
#define S_DIM 2048
#define H_DIM 16
#define DK 64
#define DM 1024
#define KDIM 1024

#define MFMA(a, b, c) __builtin_amdgcn_mfma_f32_16x16x32_bf16((a), (b), (c), 0, 0, 0)

__device__ __forceinline__ void gload_lds16(const bf16_t* g, bf16_t* l) {
    __builtin_amdgcn_global_load_lds(
        (const __attribute__((address_space(1))) void*)g,
        (__attribute__((address_space(3))) void*)l, 16, 0, 0);
}

// ---------------- fp32 -> bf16 convert ----------------
__global__ void cvt_kernel(const float* __restrict__ src, bf16_t* __restrict__ dst, int n) {
    int i = (blockIdx.x * blockDim.x + threadIdx.x) * 4;
    if (i >= n) return;
    float4 v = *reinterpret_cast<const float4*>(src + i);
    bf16x4 o;
    o[0] = (__bf16)v.x; o[1] = (__bf16)v.y; o[2] = (__bf16)v.z; o[3] = (__bf16)v.w;
    *reinterpret_cast<bf16x4*>(dst + i) = o;
}

__global__ void cvt4_kernel(const float* __restrict__ s0, const float* __restrict__ s1,
                            const float* __restrict__ s2, const float* __restrict__ s3,
                            bf16_t* __restrict__ d0, bf16_t* __restrict__ d1,
                            bf16_t* __restrict__ d2, bf16_t* __restrict__ d3, int n) {
    const float* s; bf16_t* d;
    switch (blockIdx.y) {
        case 0: s = s0; d = d0; break;
        case 1: s = s1; d = d1; break;
        case 2: s = s2; d = d2; break;
        default: s = s3; d = d3; break;
    }
    int i = (blockIdx.x * blockDim.x + threadIdx.x) * 4;
    if (i >= n) return;
    float4 v = *reinterpret_cast<const float4*>(s + i);
    bf16x4 o;
    o[0] = (__bf16)v.x; o[1] = (__bf16)v.y; o[2] = (__bf16)v.z; o[3] = (__bf16)v.w;
    *reinterpret_cast<bf16x4*>(d + i) = o;
}

// ---------------- GEMM: Y[m,n] = sum_k A[m,k] * B[n,k]  (B^T layout) ----------------
template <int MODE>
__global__ __launch_bounds__(256)
void gemm_bt(const bf16_t* __restrict__ A,
             const bf16_t* __restrict__ B0,
             const bf16_t* __restrict__ B1,
             const bf16_t* __restrict__ B2,
             bf16_t* __restrict__ outQ,
             bf16_t* __restrict__ outK,
             bf16_t* __restrict__ outVt,
             float* __restrict__ outF) {
    __shared__ bf16_t As[128 * 32];
    __shared__ bf16_t Bs[128 * 32];

    const int t = threadIdx.x;
    const int z = blockIdx.z;
    const bf16_t* Bm = (MODE == 0) ? (z == 0 ? B0 : (z == 1 ? B1 : B2)) : B0;

    const int m0 = blockIdx.x * 128;
    const int n0 = blockIdx.y * 128;
    const int lane = t & 63;
    const int w = t >> 6;
    const int wr = w >> 1;
    const int wc = w & 1;

    f32x4 acc[4][4] = {};

    const int ar = t >> 2;
    const int ac = (t & 3) * 8;
    const bf16_t* Ag = A + (size_t)m0 * KDIM;
    const bf16_t* Bg = Bm + (size_t)n0 * KDIM;

    const int rr = lane & 15;
    const int ko = (lane >> 4) * 8;

    for (int k0 = 0; k0 < KDIM; k0 += 32) {
        gload_lds16(Ag + (size_t)ar * KDIM + k0 + ac,        &As[t * 8]);
        gload_lds16(Ag + (size_t)(ar + 64) * KDIM + k0 + ac, &As[2048 + t * 8]);
        gload_lds16(Bg + (size_t)ar * KDIM + k0 + ac,        &Bs[t * 8]);
        gload_lds16(Bg + (size_t)(ar + 64) * KDIM + k0 + ac, &Bs[2048 + t * 8]);
        __syncthreads();

        bf16x8 af[4], bfr[4];
#pragma unroll
        for (int m = 0; m < 4; ++m)
            af[m] = *reinterpret_cast<const bf16x8*>(&As[(wr * 64 + m * 16 + rr) * 32 + ko]);
#pragma unroll
        for (int n = 0; n < 4; ++n)
            bfr[n] = *reinterpret_cast<const bf16x8*>(&Bs[(wc * 64 + n * 16 + rr) * 32 + ko]);
#pragma unroll
        for (int m = 0; m < 4; ++m)
#pragma unroll
            for (int n = 0; n < 4; ++n)
                acc[m][n] = MFMA(af[m], bfr[n], acc[m][n]);
        __syncthreads();
    }

    const int rbase = m0 + wr * 64 + (lane >> 4) * 4;
    const int cbase = n0 + wc * 64 + (lane & 15);
#pragma unroll
    for (int m = 0; m < 4; ++m) {
#pragma unroll
        for (int n = 0; n < 4; ++n) {
            const int gn = cbase + n * 16;
            if (MODE == 0) {
                const int h = gn >> 6, d = gn & 63;
                if (z < 2) {
                    bf16_t* dst = (z == 0) ? outQ : outK;
#pragma unroll
                    for (int j = 0; j < 4; ++j) {
                        const int gm = rbase + m * 16 + j;
                        const int b = gm >> 11, s = gm & (S_DIM - 1);
                        dst[(((size_t)(b * H_DIM + h) * S_DIM + s) << 6) + d] = (__bf16)acc[m][n][j];
                    }
                } else {
                    bf16x4 v;
#pragma unroll
                    for (int j = 0; j < 4; ++j) v[j] = (__bf16)acc[m][n][j];
                    const int gm = rbase + m * 16;
                    const int b = gm >> 11, s = gm & (S_DIM - 1);
                    *reinterpret_cast<bf16x4*>(
                        &outVt[((size_t)(b * H_DIM + h) * DK + d) * S_DIM + s]) = v;
                }
            } else {
#pragma unroll
                for (int j = 0; j < 4; ++j) {
                    const int gm = rbase + m * 16 + j;
                    outF[(size_t)gm * DM + gn] = acc[m][n][j];
                }
            }
        }
    }
}

// ---------------- RoPE (in-place, vectorized: 4 pairs / thread) ----------------
__global__ void rope_kernel(bf16_t* __restrict__ Q, bf16_t* __restrict__ Kb,
                            const int* __restrict__ pos, int total8) {
    int idx = blockIdx.x * blockDim.x + threadIdx.x;
    if (idx >= total8) return;
    const int d0 = (idx & 7) * 8;            // elem offset within head dim (0,8,..,56)
    const int s = (idx >> 3) & (S_DIM - 1);  // seq position
    const float p = (float)pos[s];
    const size_t base = (size_t)idx * 8;
    bf16x8 q = *reinterpret_cast<const bf16x8*>(&Q[base]);
    bf16x8 k = *reinterpret_cast<const bf16x8*>(&Kb[base]);
#pragma unroll
    for (int jj = 0; jj < 4; ++jj) {
        const int j = (d0 >> 1) + jj;        // pair index 0..31
        const float freq = exp2f((float)j * (-13.287712379549449f / 32.0f));
        const float ang = p * freq;
        const float sn = sinf(ang), cs = cosf(ang);
        const float q1 = (float)q[jj * 2], q2 = (float)q[jj * 2 + 1];
        q[jj * 2]     = (__bf16)(q1 * cs - q2 * sn);
        q[jj * 2 + 1] = (__bf16)(q1 * sn + q2 * cs);
        const float k1 = (float)k[jj * 2], k2 = (float)k[jj * 2 + 1];
        k[jj * 2]     = (__bf16)(k1 * cs - k2 * sn);
        k[jj * 2 + 1] = (__bf16)(k1 * sn + k2 * cs);
    }
    *reinterpret_cast<bf16x8*>(&Q[base]) = q;
    *reinterpret_cast<bf16x8*>(&Kb[base]) = k;
}

// ---------------- causal flash attention v7: paired q-blocks, lean softmax ----
// v6 structure (paired q-blocks, dual chains, K/V dbuf XOR-swizzled LDS) plus:
//  - Q pre-scaled by 0.125*log2(e): scores in log2 units -> p = exp2(s - m),
//    no per-score multiply; rescale = exp2(m - mnew).
//  - row-sum l via ones-MFMA (lacc = mfma(ones, pf, lacc)) -> no psum adds,
//    no cross-lane l reduction (MFMA reduces over full K).
//  - tree max (max3-fusable).
__global__ __launch_bounds__(256)
void attn_kernel(const bf16_t* __restrict__ Q, const bf16_t* __restrict__ Kg,
                 const bf16_t* __restrict__ Vt, bf16_t* __restrict__ O) {
    constexpr int PSTR = 72;
    __shared__ bf16_t Ks[2][64 * 64];
    __shared__ bf16_t Vs[2][64 * 64];
    __shared__ bf16_t P_lds[4][2][16 * PSTR];

    const int t = threadIdx.x;
    const int lane = t & 63;
    const int w = t >> 6;
    const int bh = blockIdx.x >> 4;   // 32 (b,h)
    const int qi = blockIdx.x & 15;
    const int qbH = 31 - qi, qbL = qi;
    const int q0H = qbH * 64 + w * 16;
    const int q0L = qbL * 64 + w * 16;
    const int b = bh >> 4, h = bh & 15;
    const int rr = lane & 15;
    const int hi = lane >> 4;

    const bf16_t* Kbh = Kg + (size_t)bh * S_DIM * DK;
    const bf16_t* Vbh = Vt + (size_t)bh * DK * S_DIM;   // [d][s]
    bf16_t* PwH = P_lds[w][0];
    bf16_t* PwL = P_lds[w][1];

    const int i0 = t, i1 = t + 256;
    const int r0 = i0 >> 3, c0 = ((i0 & 7) ^ (r0 & 7)) * 8;
    const int r1 = i1 >> 3, c1 = ((i1 & 7) ^ (r1 & 7)) * 8;

    // Q fragments, folded scale = (1/8) * log2(e)  -> scores in log2 units
    const float QSCALE = 0.18033688011112042f;
    const bf16_t* QpH = Q + ((size_t)bh * S_DIM + q0H) * DK;
    const bf16_t* QpL = Q + ((size_t)bh * S_DIM + q0L) * DK;
    bf16x8 qfH[2], qfL[2];
    qfH[0] = *reinterpret_cast<const bf16x8*>(&QpH[rr * DK + hi * 8]);
    qfH[1] = *reinterpret_cast<const bf16x8*>(&QpH[rr * DK + 32 + hi * 8]);
    qfL[0] = *reinterpret_cast<const bf16x8*>(&QpL[rr * DK + hi * 8]);
    qfL[1] = *reinterpret_cast<const bf16x8*>(&QpL[rr * DK + 32 + hi * 8]);
#pragma unroll
    for (int i = 0; i < 8; ++i) {
        qfH[0][i] = (__bf16)((float)qfH[0][i] * QSCALE);
        qfH[1][i] = (__bf16)((float)qfH[1][i] * QSCALE);
        qfL[0][i] = (__bf16)((float)qfL[0][i] * QSCALE);
        qfL[1][i] = (__bf16)((float)qfL[1][i] * QSCALE);
    }

    bf16x8 ones;
#pragma unroll
    for (int i = 0; i < 8; ++i) ones[i] = (__bf16)1.0f;

    f32x4 oH[4] = {}, oL[4] = {};
    f32x4 laH = {}, laL = {};
    float mH = -INFINITY, mL = -INFINITY;

    const int ntH = qbH + 1;

    gload_lds16(Kbh + (size_t)r0 * DK + c0, &Ks[0][i0 * 8]);
    gload_lds16(Kbh + (size_t)r1 * DK + c1, &Ks[0][i1 * 8]);
    gload_lds16(Vbh + (size_t)r0 * S_DIM + c0, &Vs[0][i0 * 8]);
    gload_lds16(Vbh + (size_t)r1 * S_DIM + c1, &Vs[0][i1 * 8]);
    __syncthreads();

    for (int tt = 0; tt < ntH; ++tt) {
        const int cur = tt & 1;
        const int kv0 = tt * 64;
        const bool doL = (tt <= qbL);

        if (tt + 1 < ntH) {
            const int kv1 = kv0 + 64;
            bf16_t* Kn = Ks[cur ^ 1];
            bf16_t* Vn = Vs[cur ^ 1];
            gload_lds16(Kbh + (size_t)(kv1 + r0) * DK + c0, &Kn[i0 * 8]);
            gload_lds16(Kbh + (size_t)(kv1 + r1) * DK + c1, &Kn[i1 * 8]);
            gload_lds16(Vbh + (size_t)r0 * S_DIM + kv1 + c0, &Vn[i0 * 8]);
            gload_lds16(Vbh + (size_t)r1 * S_DIM + kv1 + c1, &Vn[i1 * 8]);
        }
        const bf16_t* Kc = Ks[cur];
        const bf16_t* Vc = Vs[cur];

        // QK^T (scores in log2 units), both chains share K fragments
        f32x4 sH[4] = {}, sL[4] = {};
        __builtin_amdgcn_s_setprio(1);
#pragma unroll
        for (int t16 = 0; t16 < 4; ++t16) {
            const int r = t16 * 16 + rr;
            const int sw = (r & 7) * 8;
            bf16x8 kf0 = *reinterpret_cast<const bf16x8*>(&Kc[r * 64 + ((hi * 8) ^ sw)]);
            bf16x8 kf1 = *reinterpret_cast<const bf16x8*>(&Kc[r * 64 + ((32 + hi * 8) ^ sw)]);
            sH[t16] = MFMA(kf0, qfH[0], sH[t16]);
            sH[t16] = MFMA(kf1, qfH[1], sH[t16]);
            if (doL) {
                sL[t16] = MFMA(kf0, qfL[0], sL[t16]);
                sL[t16] = MFMA(kf1, qfL[1], sL[t16]);
            }
        }
        __builtin_amdgcn_s_setprio(0);

        if (tt == qbH) {
            const int qg = q0H + rr;
#pragma unroll
            for (int t16 = 0; t16 < 4; ++t16)
#pragma unroll
                for (int j = 0; j < 4; ++j)
                    if (kv0 + t16 * 16 + hi * 4 + j > qg) sH[t16][j] = -INFINITY;
        }
        if (tt == qbL) {
            const int qg = q0L + rr;
#pragma unroll
            for (int t16 = 0; t16 < 4; ++t16)
#pragma unroll
                for (int j = 0; j < 4; ++j)
                    if (kv0 + t16 * 16 + hi * 4 + j > qg) sL[t16][j] = -INFINITY;
        }

        // ---- softmax H ----
        {
            f32x4 mv = sH[0];
#pragma unroll
            for (int t16 = 1; t16 < 4; ++t16) {
                mv[0] = fmaxf(mv[0], sH[t16][0]); mv[1] = fmaxf(mv[1], sH[t16][1]);
                mv[2] = fmaxf(mv[2], sH[t16][2]); mv[3] = fmaxf(mv[3], sH[t16][3]);
            }
            const float mloc = fmaxf(fmaxf(mv[0], mv[1]), fmaxf(mv[2], mv[3]));
            if (__any(mloc - mH > 8.0f)) {
                float mf = fmaxf(mloc, __shfl_xor(mloc, 16));
                mf = fmaxf(mf, __shfl_xor(mf, 32));
                const float mnew = fmaxf(mH, mf);
                const float scale = exp2f(mH - mnew);
#pragma unroll
                for (int i = 0; i < 4; ++i) laH[i] *= scale;
#pragma unroll
                for (int db = 0; db < 4; ++db)
#pragma unroll
                    for (int j = 0; j < 4; ++j) oH[db][j] *= scale;
                mH = mnew;
            }
#pragma unroll
            for (int t16 = 0; t16 < 4; ++t16) {
                bf16x4 pb;
#pragma unroll
                for (int j = 0; j < 4; ++j) pb[j] = (__bf16)exp2f(sH[t16][j] - mH);
                *reinterpret_cast<bf16x4*>(&PwH[rr * PSTR + t16 * 16 + hi * 4]) = pb;
            }
        }
        // ---- softmax L ----
        if (doL) {
            f32x4 mv = sL[0];
#pragma unroll
            for (int t16 = 1; t16 < 4; ++t16) {
                mv[0] = fmaxf(mv[0], sL[t16][0]); mv[1] = fmaxf(mv[1], sL[t16][1]);
                mv[2] = fmaxf(mv[2], sL[t16][2]); mv[3] = fmaxf(mv[3], sL[t16][3]);
            }
            const float mloc = fmaxf(fmaxf(mv[0], mv[1]), fmaxf(mv[2], mv[3]));
            if (__any(mloc - mL > 8.0f)) {
                float mf = fmaxf(mloc, __shfl_xor(mloc, 16));
                mf = fmaxf(mf, __shfl_xor(mf, 32));
                const float mnew = fmaxf(mL, mf);
                const float scale = exp2f(mL - mnew);
#pragma unroll
                for (int i = 0; i < 4; ++i) laL[i] *= scale;
#pragma unroll
                for (int db = 0; db < 4; ++db)
#pragma unroll
                    for (int j = 0; j < 4; ++j) oL[db][j] *= scale;
                mL = mnew;
            }
#pragma unroll
            for (int t16 = 0; t16 < 4; ++t16) {
                bf16x4 pb;
#pragma unroll
                for (int j = 0; j < 4; ++j) pb[j] = (__bf16)exp2f(sL[t16][j] - mL);
                *reinterpret_cast<bf16x4*>(&PwL[rr * PSTR + t16 * 16 + hi * 4]) = pb;
            }
        }

        // ---- PV + l via ones-MFMA, both chains share V fragments ----
        bf16x8 pH0 = *reinterpret_cast<const bf16x8*>(&PwH[rr * PSTR + hi * 8]);
        bf16x8 pH1 = *reinterpret_cast<const bf16x8*>(&PwH[rr * PSTR + 32 + hi * 8]);
        bf16x8 pL0, pL1;
        if (doL) {
            pL0 = *reinterpret_cast<const bf16x8*>(&PwL[rr * PSTR + hi * 8]);
            pL1 = *reinterpret_cast<const bf16x8*>(&PwL[rr * PSTR + 32 + hi * 8]);
        }
        __builtin_amdgcn_s_setprio(1);
        laH = MFMA(ones, pH0, laH);
        laH = MFMA(ones, pH1, laH);
        if (doL) {
            laL = MFMA(ones, pL0, laL);
            laL = MFMA(ones, pL1, laL);
        }
#pragma unroll
        for (int db = 0; db < 4; ++db) {
            const int vr = db * 16 + rr;
            const int sw = (vr & 7) * 8;
            bf16x8 vf0 = *reinterpret_cast<const bf16x8*>(&Vc[vr * 64 + ((hi * 8) ^ sw)]);
            bf16x8 vf1 = *reinterpret_cast<const bf16x8*>(&Vc[vr * 64 + ((32 + hi * 8) ^ sw)]);
            oH[db] = MFMA(vf0, pH0, oH[db]);
            oH[db] = MFMA(vf1, pH1, oH[db]);
            if (doL) {
                oL[db] = MFMA(vf0, pL0, oL[db]);
                oL[db] = MFMA(vf1, pL1, oL[db]);
            }
        }
        __builtin_amdgcn_s_setprio(0);

        __syncthreads();
    }

    // epilogue (l = laX[0]: complete row sum, no cross-lane reduce needed)
    {
        const float linv = 1.0f / laH[0];
#pragma unroll
        for (int db = 0; db < 4; ++db) {
            bf16x4 ov;
#pragma unroll
            for (int j = 0; j < 4; ++j) ov[j] = (__bf16)(oH[db][j] * linv);
            *reinterpret_cast<bf16x4*>(
                &O[((size_t)(b * S_DIM + q0H + rr)) * DM + h * DK + db * 16 + hi * 4]) = ov;
        }
    }
    {
        const float linv = 1.0f / laL[0];
#pragma unroll
        for (int db = 0; db < 4; ++db) {
            bf16x4 ov;
#pragma unroll
            for (int j = 0; j < 4; ++j) ov[j] = (__bf16)(oL[db][j] * linv);
            *reinterpret_cast<bf16x4*>(
                &O[((size_t)(b * S_DIM + q0L + rr)) * DM + h * DK + db * 16 + hi * 4]) = ov;
        }
    }
}

extern "C" void kernel_launch(void* const* d_in, const int* in_sizes, int n_in,
                              void* d_out, int out_size, void* d_ws, size_t ws_size,
                              hipStream_t stream) {
    const float* x  = (const float*)d_in[0];
    const float* Wq = (const float*)d_in[1];
    const float* Wk = (const float*)d_in[2];
    const float* Wv = (const float*)d_in[3];
    const float* Wo = (const float*)d_in[4];
    const int* pos  = (const int*)d_in[5];
    float* out = (float*)d_out;

    char* ws = (char*)d_ws;
    bf16_t* xb  = (bf16_t*)(ws);
    bf16_t* Wqb = (bf16_t*)(ws + (8u << 20));
    bf16_t* Wkb = (bf16_t*)(ws + (10u << 20));
    bf16_t* Wvb = (bf16_t*)(ws + (12u << 20));
    bf16_t* Wob = (bf16_t*)(ws + (14u << 20));
    bf16_t* Qb  = (bf16_t*)(ws + (16u << 20));
    bf16_t* Kb  = (bf16_t*)(ws + (24u << 20));
    bf16_t* Vtb = (bf16_t*)(ws + (32u << 20));
    bf16_t* Ab  = (bf16_t*)(ws);  // reuse xb region after QKV GEMM

    const int NX = B_DIM * S_DIM * DM;
    const int NW = DM * DM;

    cvt_kernel<<<NX / 1024, 256, 0, stream>>>(x, xb, NX);
    cvt4_kernel<<<dim3(NW / 1024, 4), 256, 0, stream>>>(Wq, Wk, Wv, Wo,
                                                        Wqb, Wkb, Wvb, Wob, NW);

    gemm_bt<0><<<dim3(32, 8, 3), 256, 0, stream>>>(xb, Wqb, Wkb, Wvb, Qb, Kb, Vtb, nullptr);

    const int total8 = B_DIM * H_DIM * S_DIM * 8;  // 64 elems / 8 per thread
    rope_kernel<<<total8 / 256, 256, 0, stream>>>(Qb, Kb, pos, total8);

    attn_kernel<<<B_DIM * H_DIM * 16, 256, 0, stream>>>(Qb, Kb, Vtb, Ab);

    gemm_bt<1><<<dim3(32, 8, 1), 256, 0, stream>>>(Ab, Wob, nullptr, nullptr,
                                                   nullptr, nullptr, nullptr, out);
}